// Round 7
// baseline (860.124 us; speedup 1.0000x reference)
//
#include <hip/hip_runtime.h>

#define BQ 256
#define TQ 1024
#define FQ 37
#define UQ 64
#define G3 192
#define CH 8
#define NCK (TQ / CH)   // 128 chunks

__device__ __forceinline__ float sigmoid_f(float x) {
    return 1.0f / (1.0f + __expf(-x));
}
__device__ __forceinline__ float tanh_f(float x) {
    return 1.0f - 2.0f / (__expf(2.0f * x) + 1.0f);
}

// 2 waves per block, producer/consumer (R6 structure) + REGISTER UNION:
// W0/W1/W2 are one shared register file for both divergent wave roles, so the
// path-insensitive allocator sees ~210 live regs instead of ~330 (R6 spilled
// ~220 dwords/thread to scratch: WRITE_SIZE 29MB, VGPR capped 256).
//  wave0 (consumer): W*[u] = Wr columns j/64+j/128+j; lane-local GRU step,
//        h broadcast via readlane (SGPR, no VGPR cost). No per-step barrier.
//  wave1 (producer): W*[f<37] = Wk columns; W0[40..44] staging; W1[40..47]
//        dense-w. Stages values 2 chunks ahead, xp 1 chunk ahead, head 1 behind.
//  Sync: ONE s_barrier per 8 steps.
__global__ __launch_bounds__(128)
__attribute__((amdgpu_waves_per_eu(1, 1)))
void gru_pc(const float* __restrict__ values,   // [B,T,F]
            const int*   __restrict__ lengths,  // [B]
            const float* __restrict__ Wk,       // [F,3U]
            const float* __restrict__ Wr,       // [U,3U]
            const float* __restrict__ bias,     // [2,3U]
            const float* __restrict__ dw,       // [U]
            const float* __restrict__ db,       // [1]
            float*       __restrict__ out)      // [B,T]
{
    const int tid = threadIdx.x;
    const int j   = tid & 63;
    const int w   = tid >> 6;
    const int b   = blockIdx.x;

    __shared__ __align__(16) float s_v[2][CH][40];   // staged values (dbuf)
    __shared__ float s_xp[2][CH][G3];                // x-projections (dbuf)
    __shared__ __align__(16) float s_h8[2][CH][76];  // h history (padded rows)

    const float* vbp = values + (size_t)b * TQ * FQ;
    float* ob = out + (size_t)b * TQ;

    // ---- the shared (union) register arrays ----
    float W0[64], W1[64], W2[64];
    float bz = 0.f, br = 0.f, bh = 0.f, dbv = 0.f;
    int len = 0;
    int rq[5], cq[5];

#define XF(VX, F) az += (VX) * W0[F]; ar += (VX) * W1[F]; ah += (VX) * W2[F];
// x-projection of one staged row; two halves to cap live temps (~24)
#define XPROW(PB, ROW)                                                        \
    {                                                                         \
        const float4* vr = (const float4*)&s_v[PB][ROW][0];                   \
        float az = bz, ar = br, ah = bh;                                      \
        {                                                                     \
            float4 v0 = vr[0], v1 = vr[1], v2 = vr[2], v3 = vr[3], v4 = vr[4];\
            XF(v0.x, 0)  XF(v0.y, 1)  XF(v0.z, 2)  XF(v0.w, 3)                \
            XF(v1.x, 4)  XF(v1.y, 5)  XF(v1.z, 6)  XF(v1.w, 7)                \
            XF(v2.x, 8)  XF(v2.y, 9)  XF(v2.z, 10) XF(v2.w, 11)               \
            XF(v3.x, 12) XF(v3.y, 13) XF(v3.z, 14) XF(v3.w, 15)               \
            XF(v4.x, 16) XF(v4.y, 17) XF(v4.z, 18) XF(v4.w, 19)               \
        }                                                                     \
        {                                                                     \
            float4 v5 = vr[5], v6 = vr[6], v7 = vr[7], v8 = vr[8];            \
            float v36 = s_v[PB][ROW][36];                                     \
            XF(v5.x, 20) XF(v5.y, 21) XF(v5.z, 22) XF(v5.w, 23)               \
            XF(v6.x, 24) XF(v6.y, 25) XF(v6.z, 26) XF(v6.w, 27)               \
            XF(v7.x, 28) XF(v7.y, 29) XF(v7.z, 30) XF(v7.w, 31)               \
            XF(v8.x, 32) XF(v8.y, 33) XF(v8.z, 34) XF(v8.w, 35)               \
            XF(v36, 36)                                                       \
        }                                                                     \
        s_xp[PB][ROW][j]       = az;                                          \
        s_xp[PB][ROW][64 + j]  = ar;                                          \
        s_xp[PB][ROW][128 + j] = ah;                                          \
    }

#define HEAD(HB, TB)                                                          \
    {                                                                         \
        const int e = j & 7, s = j >> 3;                                      \
        const float4* hr = (const float4*)&s_h8[HB][s][e * 8];                \
        float4 ha = hr[0], hc = hr[1];                                        \
        float p = ha.x * W1[40] + ha.y * W1[41] + ha.z * W1[42]               \
                + ha.w * W1[43] + hc.x * W1[44] + hc.y * W1[45]               \
                + hc.z * W1[46] + hc.w * W1[47];                              \
        p += __shfl_xor(p, 1, 64);                                            \
        p += __shfl_xor(p, 2, 64);                                            \
        p += __shfl_xor(p, 4, 64);                                            \
        if (e == 0) ob[(TB) + s] = sigmoid_f(p + dbv);                        \
    }

    if (w == 0) {
        // consumer: recurrent weight columns j / 64+j / 128+j
#pragma unroll
        for (int u = 0; u < UQ; ++u) {
            W0[u] = Wr[u * G3 + j];
            W1[u] = Wr[u * G3 + 64 + j];
            W2[u] = Wr[u * G3 + 128 + j];
        }
        bz = bias[G3 + j];
        br = bias[G3 + 64 + j];
        bh = bias[G3 + 128 + j];
        len = lengths[b];
    } else {
        // producer: input weight columns + staging + dense head weights
#pragma unroll
        for (int f = 0; f < FQ; ++f) {
            W0[f] = Wk[f * G3 + j];
            W1[f] = Wk[f * G3 + 64 + j];
            W2[f] = Wk[f * G3 + 128 + j];
        }
        bz = bias[j];
        br = bias[64 + j];
        bh = bias[128 + j];
        dbv = db[0];
#pragma unroll
        for (int i = 0; i < 8; ++i) W1[40 + i] = dw[(j & 7) * 8 + i];
#pragma unroll
        for (int q = 0; q < 5; ++q) {
            const int idx = j + 64 * q;
            rq[q] = idx / FQ;
            cq[q] = idx - rq[q] * FQ;
        }
        // prologue: stage chunk 0, issue chunk 1, xp(chunk 0)
#pragma unroll
        for (int q = 0; q < 5; ++q) {
            const int idx = j + 64 * q;
            if (idx < CH * FQ) W0[40 + q] = vbp[idx];
        }
        asm volatile("s_waitcnt vmcnt(0)" ::: "memory");
#pragma unroll
        for (int q = 0; q < 5; ++q)
            if (j + 64 * q < CH * FQ) s_v[0][rq[q]][cq[q]] = W0[40 + q];
#pragma unroll
        for (int q = 0; q < 5; ++q) {
            const int idx = j + 64 * q;
            if (idx < CH * FQ) W0[40 + q] = vbp[CH * FQ + idx];
        }
        asm volatile("s_waitcnt lgkmcnt(0)" ::: "memory");  // my s_v writes visible
#pragma unroll 1
        for (int s = 0; s < CH; ++s) XPROW(0, s)
    }
    asm volatile("s_waitcnt lgkmcnt(0)" ::: "memory");
    __builtin_amdgcn_s_barrier();      // xp[0] visible to consumer

    float h = 0.0f;                    // wave0: lane j holds h_j

#pragma unroll 1
    for (int k = 0; k < NCK; ++k) {
        const int pb = k & 1;
        if (w == 0) {
            const int tbase = k * CH;
#pragma unroll 1
            for (int tc = 0; tc < CH; ++tc) {
                const float xz = s_xp[pb][tc][j];
                const float xr = s_xp[pb][tc][64 + j];
                const float xh = s_xp[pb][tc][128 + j];
                const int hbits = __float_as_int(h);
                float az0 = 0.f, az1 = 0.f, ar0 = 0.f, ar1 = 0.f,
                      ah0 = 0.f, ah1 = 0.f;
#pragma unroll
                for (int u = 0; u < UQ; u += 2) {
                    const float h0 = __int_as_float(
                        __builtin_amdgcn_readlane(hbits, u));
                    const float h1 = __int_as_float(
                        __builtin_amdgcn_readlane(hbits, u + 1));
                    az0 += h0 * W0[u];     az1 += h1 * W0[u + 1];
                    ar0 += h0 * W1[u];     ar1 += h1 * W1[u + 1];
                    ah0 += h0 * W2[u];     ah1 += h1 * W2[u + 1];
                }
                const float z  = sigmoid_f(xz + bz + (az0 + az1));
                const float r  = sigmoid_f(xr + br + (ar0 + ar1));
                const float cc = tanh_f(xh + r * (bh + (ah0 + ah1)));
                const float hn = z * h + (1.0f - z) * cc;
                h = ((tbase + tc) < len) ? hn : h;
                s_h8[pb][tc][j] = h;
            }
        } else {
            if (k > 0) HEAD((k - 1) & 1, (k - 1) * CH)     // head, prev chunk
            if (k + 1 < NCK) {
                asm volatile("s_waitcnt vmcnt(0)" ::: "memory");
                const int nb = (k + 1) & 1;
#pragma unroll
                for (int q = 0; q < 5; ++q)
                    if (j + 64 * q < CH * FQ) s_v[nb][rq[q]][cq[q]] = W0[40 + q];
                if (k + 2 < NCK) {                          // issue chunk k+2
#pragma unroll
                    for (int q = 0; q < 5; ++q) {
                        const int idx = j + 64 * q;
                        if (idx < CH * FQ)
                            W0[40 + q] = vbp[(k + 2) * (CH * FQ) + idx];
                    }
                }
                asm volatile("s_waitcnt lgkmcnt(0)" ::: "memory");
#pragma unroll 1
                for (int s = 0; s < CH; ++s) XPROW(nb, s)
            }
        }
        asm volatile("s_waitcnt lgkmcnt(0)" ::: "memory");
        __builtin_amdgcn_s_barrier();   // once per 8 steps
    }

    if (w == 1) HEAD((NCK - 1) & 1, (NCK - 1) * CH)         // last chunk's head

#undef XF
#undef XPROW
#undef HEAD
}

extern "C" void kernel_launch(void* const* d_in, const int* in_sizes, int n_in,
                              void* d_out, int out_size, void* d_ws, size_t ws_size,
                              hipStream_t stream) {
    const float* values  = (const float*)d_in[2];
    const int*   lengths = (const int*)  d_in[4];
    const float* Wk      = (const float*)d_in[5];
    const float* Wr      = (const float*)d_in[6];
    const float* bias    = (const float*)d_in[7];
    const float* dw      = (const float*)d_in[8];
    const float* db      = (const float*)d_in[9];
    float* out = (float*)d_out;

    gru_pc<<<dim3(BQ), dim3(128), 0, stream>>>(
        values, lengths, Wk, Wr, bias, dw, db, out);
}

// Round 8
// 685.607 us; speedup vs baseline: 1.2545x; 1.2545x over previous
//
#include <hip/hip_runtime.h>

#define BQ 256
#define TQ 1024
#define FQ 37
#define UQ 64
#define G3 192
#define CH 8
#define NCK (TQ / CH)
#define CFD (CH * FQ)   // 296 dwords per staged chunk

__device__ __forceinline__ float sigmoid_f(float x) {
    return 1.0f / (1.0f + __expf(-x));
}
__device__ __forceinline__ float tanh_f(float x) {
    return 1.0f - 2.0f / (__expf(2.0f * x) + 1.0f);
}

// 3 waves / block (one batch element):
//  wave0 consumer: lane j owns h_j + gate columns j/64+j/128+j (192 W regs,
//         union-shared). Per step: 64 readlane + 192 fma + gates. No per-step
//         barrier, no vmcnt ever on this path.
//  wave1 producer A: features 0..18 of the x-projection (57 K regs, overlaid
//         into W[0..18]); half the chunk staging.
//  wave2 producer B: features 19..36 (54 K regs overlaid); staging; dense head.
//  xp partials meet in LDS; consumer adds. ONE barrier per 8 steps.
//  Pipeline: values staged 2 chunks ahead (cross-barrier visibility), xp 1
//  chunk ahead, head 1 chunk behind.
__global__ __launch_bounds__(192)
__attribute__((amdgpu_waves_per_eu(1, 1)))
void gru3(const float* __restrict__ values,   // [B,T,F]
          const int*   __restrict__ lengths,  // [B]
          const float* __restrict__ Wk,       // [F,3U]
          const float* __restrict__ Wr,       // [U,3U]
          const float* __restrict__ bias,     // [2,3U]
          const float* __restrict__ dw,       // [U]
          const float* __restrict__ db,       // [1]
          float*       __restrict__ out)      // [B,T]
{
    const int tid = threadIdx.x;
    const int j   = tid & 63;
    const int w   = tid >> 6;
    const int b   = blockIdx.x;

    __shared__ __align__(16) float s_v[2][CH][40];   // staged values (dbuf)
    __shared__ float s_xp[2][CH][2][G3];             // xp partials [buf][row][half][col]
    __shared__ __align__(16) float s_h8[2][CH][76];  // h history (padded rows)

    const float* vbp = values + (size_t)b * TQ * FQ;
    float* ob = out + (size_t)b * TQ;

    // union register file: consumer fills [0..63]; producers overlay [0..18]
    float W0[UQ], W1[UQ], W2[UQ];
    float bz = 0.f, br = 0.f, bh = 0.f, dbv = 0.f;
    float sg0 = 0.f, sg1 = 0.f, sg2 = 0.f;           // staging regs
    float dwv[8];
    int len = 0;
    int rq0 = 0, cq0 = 0, rq1 = 0, cq1 = 0, rq2 = 0, cq2 = 0;
    bool a1 = false, a2 = false;
    int p = 0;

#define XF(VAL, I) { az += (VAL) * W0[I]; ar += (VAL) * W1[I]; ah += (VAL) * W2[I]; }

// producer A: features 0..18 (adds input bias)
#define XPROW1(BB)                                                            \
    _Pragma("unroll 1")                                                       \
    for (int row = 0; row < CH; ++row) {                                      \
        const float4* vr = (const float4*)&s_v[BB][row][0];                   \
        float az = bz, ar = br, ah = bh;                                      \
        { float4 v0 = vr[0], v1 = vr[1], v2 = vr[2];                          \
          XF(v0.x, 0)  XF(v0.y, 1)  XF(v0.z, 2)  XF(v0.w, 3)                  \
          XF(v1.x, 4)  XF(v1.y, 5)  XF(v1.z, 6)  XF(v1.w, 7)                  \
          XF(v2.x, 8)  XF(v2.y, 9)  XF(v2.z, 10) XF(v2.w, 11) }               \
        { float4 v3 = vr[3], v4 = vr[4];                                      \
          XF(v3.x, 12) XF(v3.y, 13) XF(v3.z, 14) XF(v3.w, 15)                 \
          XF(v4.x, 16) XF(v4.y, 17) XF(v4.z, 18) }                            \
        s_xp[BB][row][0][j]       = az;                                       \
        s_xp[BB][row][0][64 + j]  = ar;                                       \
        s_xp[BB][row][0][128 + j] = ah;                                       \
        __builtin_amdgcn_sched_barrier(0);                                    \
    }

// producer B: features 19..36 (no bias)
#define XPROW2(BB)                                                            \
    _Pragma("unroll 1")                                                       \
    for (int row = 0; row < CH; ++row) {                                      \
        const float4* vr = (const float4*)&s_v[BB][row][0];                   \
        float az = 0.f, ar = 0.f, ah = 0.f;                                   \
        { float4 v4 = vr[4], v5 = vr[5], v6 = vr[6];                          \
          XF(v4.w, 0)                                                         \
          XF(v5.x, 1)  XF(v5.y, 2)  XF(v5.z, 3)  XF(v5.w, 4)                  \
          XF(v6.x, 5)  XF(v6.y, 6)  XF(v6.z, 7)  XF(v6.w, 8) }               \
        { float4 v7 = vr[7], v8 = vr[8];                                      \
          float f36 = s_v[BB][row][36];                                       \
          XF(v7.x, 9)  XF(v7.y, 10) XF(v7.z, 11) XF(v7.w, 12)                 \
          XF(v8.x, 13) XF(v8.y, 14) XF(v8.z, 15) XF(v8.w, 16)                 \
          XF(f36, 17) }                                                       \
        s_xp[BB][row][1][j]       = az;                                       \
        s_xp[BB][row][1][64 + j]  = ar;                                       \
        s_xp[BB][row][1][128 + j] = ah;                                       \
        __builtin_amdgcn_sched_barrier(0);                                    \
    }

#define HEAD(HB, TB)                                                          \
    {                                                                         \
        const int e = j & 7, s = j >> 3;                                      \
        const float4* hr = (const float4*)&s_h8[HB][s][e * 8];                \
        float4 ha = hr[0], hc = hr[1];                                        \
        float pp = ha.x * dwv[0] + ha.y * dwv[1] + ha.z * dwv[2]              \
                 + ha.w * dwv[3] + hc.x * dwv[4] + hc.y * dwv[5]              \
                 + hc.z * dwv[6] + hc.w * dwv[7];                             \
        pp += __shfl_xor(pp, 1, 64);                                          \
        pp += __shfl_xor(pp, 2, 64);                                          \
        pp += __shfl_xor(pp, 4, 64);                                          \
        if (e == 0) ob[(TB) + s] = sigmoid_f(pp + dbv);                       \
    }

#pragma unroll
    for (int i = 0; i < 8; ++i) dwv[i] = 0.0f;

    if (w == 0) {
        // consumer: recurrent columns j / 64+j / 128+j
#pragma unroll 1
        for (int u = 0; u < UQ; ++u) {
            W0[u] = Wr[u * G3 + j];
            W1[u] = Wr[u * G3 + 64 + j];
            W2[u] = Wr[u * G3 + 128 + j];
        }
        bz = bias[G3 + j];
        br = bias[G3 + 64 + j];
        bh = bias[G3 + 128 + j];
        len = lengths[b];
    } else {
        if (w == 1) {
#pragma unroll 1
            for (int i = 0; i < 19; ++i) {
                W0[i] = Wk[i * G3 + j];
                W1[i] = Wk[i * G3 + 64 + j];
                W2[i] = Wk[i * G3 + 128 + j];
            }
            bz = bias[j];
            br = bias[64 + j];
            bh = bias[128 + j];
        } else {
#pragma unroll 1
            for (int i = 0; i < 18; ++i) {
                W0[i] = Wk[(19 + i) * G3 + j];
                W1[i] = Wk[(19 + i) * G3 + 64 + j];
                W2[i] = Wk[(19 + i) * G3 + 128 + j];
            }
#pragma unroll
            for (int i = 0; i < 8; ++i) dwv[i] = dw[(j & 7) * 8 + i];
            dbv = db[0];
        }
        // staging geometry: producer lane p covers dwords p, p+128, p+256
        p = (w - 1) * 64 + j;
        a1 = (p + 128) < CFD;
        a2 = (p + 256) < CFD;
        rq0 = p / FQ;          cq0 = p - rq0 * FQ;
        rq1 = (p + 128) / FQ;  cq1 = (p + 128) - rq1 * FQ;
        rq2 = (p + 256) / FQ;  cq2 = (p + 256) - rq2 * FQ;

        // prologue: chunk0 -> s_v[0]; chunk1 -> s_v[1]; issue chunk2
        sg0 = vbp[p];
        if (a1) sg1 = vbp[p + 128];
        if (a2) sg2 = vbp[p + 256];
        asm volatile("s_waitcnt vmcnt(0)" ::: "memory");
        __builtin_amdgcn_sched_barrier(0);
        s_v[0][rq0][cq0] = sg0;
        if (a1) s_v[0][rq1][cq1] = sg1;
        if (a2) s_v[0][rq2][cq2] = sg2;
        sg0 = vbp[CFD + p];
        if (a1) sg1 = vbp[CFD + p + 128];
        if (a2) sg2 = vbp[CFD + p + 256];
        asm volatile("s_waitcnt vmcnt(0)" ::: "memory");
        __builtin_amdgcn_sched_barrier(0);
        s_v[1][rq0][cq0] = sg0;
        if (a1) s_v[1][rq1][cq1] = sg1;
        if (a2) s_v[1][rq2][cq2] = sg2;
        sg0 = vbp[2 * CFD + p];
        if (a1) sg1 = vbp[2 * CFD + p + 128];
        if (a2) sg2 = vbp[2 * CFD + p + 256];
    }
    asm volatile("s_waitcnt lgkmcnt(0)" ::: "memory");
    __builtin_amdgcn_sched_barrier(0);
    __builtin_amdgcn_s_barrier();            // s_v[0], s_v[1] visible block-wide

    if (w == 1) { XPROW1(0) }
    if (w == 2) { XPROW2(0) }
    asm volatile("s_waitcnt lgkmcnt(0)" ::: "memory");
    __builtin_amdgcn_sched_barrier(0);
    __builtin_amdgcn_s_barrier();            // xp[0] visible

    float h = 0.0f;                          // wave0: lane j holds h_j

#pragma unroll 1
    for (int k = 0; k < NCK; ++k) {
        const int pb = k & 1, nb = pb ^ 1;
        if (w == 0) {
            const int tbase = k * CH;
            // 1-step-ahead xp prefetch rotation
            float cz0 = s_xp[pb][0][0][j],       cz1 = s_xp[pb][0][1][j];
            float cr0 = s_xp[pb][0][0][64 + j],  cr1 = s_xp[pb][0][1][64 + j];
            float ch0 = s_xp[pb][0][0][128 + j], ch1 = s_xp[pb][0][1][128 + j];
#pragma unroll 1
            for (int tc = 0; tc < CH; ++tc) {
                const int tn = (tc + 1) & (CH - 1);   // tc=7 reads row0 (unused)
                const float nz0 = s_xp[pb][tn][0][j];
                const float nz1 = s_xp[pb][tn][1][j];
                const float nr0 = s_xp[pb][tn][0][64 + j];
                const float nr1 = s_xp[pb][tn][1][64 + j];
                const float nh0 = s_xp[pb][tn][0][128 + j];
                const float nh1 = s_xp[pb][tn][1][128 + j];

                const int hbits = __float_as_int(h);
                float az0 = 0.f, az1 = 0.f, ar0 = 0.f, ar1 = 0.f,
                      ah0 = 0.f, ah1 = 0.f;
#pragma unroll
                for (int u = 0; u < UQ; u += 2) {
                    const float h0 = __int_as_float(
                        __builtin_amdgcn_readlane(hbits, u));
                    const float h1 = __int_as_float(
                        __builtin_amdgcn_readlane(hbits, u + 1));
                    az0 += h0 * W0[u];     az1 += h1 * W0[u + 1];
                    ar0 += h0 * W1[u];     ar1 += h1 * W1[u + 1];
                    ah0 += h0 * W2[u];     ah1 += h1 * W2[u + 1];
                    if ((u & 15) == 14) __builtin_amdgcn_sched_barrier(0);
                }
                const float z  = sigmoid_f(cz0 + cz1 + bz + az0 + az1);
                const float r  = sigmoid_f(cr0 + cr1 + br + ar0 + ar1);
                const float cc = tanh_f(ch0 + ch1 + r * (bh + ah0 + ah1));
                const float hn = z * h + (1.0f - z) * cc;
                h = ((tbase + tc) < len) ? hn : h;
                s_h8[pb][tc][j] = h;

                cz0 = nz0; cz1 = nz1; cr0 = nr0; cr1 = nr1; ch0 = nh0; ch1 = nh1;
            }
        } else {
            if (w == 2 && k > 0) HEAD((k - 1) & 1, (k - 1) * CH)
            if (k + 2 < NCK) {
                asm volatile("s_waitcnt vmcnt(0)" ::: "memory");
                __builtin_amdgcn_sched_barrier(0);
                s_v[pb][rq0][cq0] = sg0;             // chunk k+2 (parity pb)
                if (a1) s_v[pb][rq1][cq1] = sg1;
                if (a2) s_v[pb][rq2][cq2] = sg2;
                if (k + 3 < NCK) {                   // issue chunk k+3
                    const size_t base = (size_t)(k + 3) * CFD;
                    sg0 = vbp[base + p];
                    if (a1) sg1 = vbp[base + p + 128];
                    if (a2) sg2 = vbp[base + p + 256];
                }
            }
            if (k + 1 < NCK) {
                if (w == 1) { XPROW1(nb) }           // xp chunk k+1 from s_v[nb]
                else        { XPROW2(nb) }
            }
        }
        asm volatile("s_waitcnt lgkmcnt(0)" ::: "memory");
        __builtin_amdgcn_sched_barrier(0);
        __builtin_amdgcn_s_barrier();                // once per 8 steps
    }

    if (w == 2) HEAD((NCK - 1) & 1, (NCK - 1) * CH)

#undef XF
#undef XPROW1
#undef XPROW2
#undef HEAD
}

extern "C" void kernel_launch(void* const* d_in, const int* in_sizes, int n_in,
                              void* d_out, int out_size, void* d_ws, size_t ws_size,
                              hipStream_t stream) {
    const float* values  = (const float*)d_in[2];
    const int*   lengths = (const int*)  d_in[4];
    const float* Wk      = (const float*)d_in[5];
    const float* Wr      = (const float*)d_in[6];
    const float* bias    = (const float*)d_in[7];
    const float* dw      = (const float*)d_in[8];
    const float* db      = (const float*)d_in[9];
    float* out = (float*)d_out;

    gru3<<<dim3(BQ), dim3(192), 0, stream>>>(
        values, lengths, Wk, Wr, bias, dw, db, out);
}

// Round 9
// 680.155 us; speedup vs baseline: 1.2646x; 1.0080x over previous
//
#include <hip/hip_runtime.h>

#define BQ 256
#define TQ 1024
#define FQ 37
#define UQ 64
#define G3 192
#define CH 8
#define NCK (TQ / CH)
#define CFD (CH * FQ)   // 296 dwords per staged chunk

__device__ __forceinline__ float sigmoid_f(float x) {
    return 1.0f / (1.0f + __expf(-x));
}
__device__ __forceinline__ float tanh_f(float x) {
    return 1.0f - 2.0f / (__expf(2.0f * x) + 1.0f);
}

// 2 waves / block (one batch element), producer/consumer with DISJOINT LOOPS:
// each role owns a complete copy of the k-loop inside its own branch, so the
// consumer's 192 weight regs and the producer's ~130 regs never interfere
// (R6-R8: fused loop bodies made the sets co-live -> allocator spilled to
// scratch; R8 VGPR=148<192 proved weights were never resident).
//  wave0 consumer: lane j owns h_j + gate columns j/64+j/128+j. Per step:
//        64 readlane (h broadcast) + 192 fma + gates. Reads xp from LDS with
//        1-step rotation prefetch. No vmcnt ever. One barrier per 8 steps.
//  wave1 producer: stages values 2 chunks ahead (5 regs), computes full
//        x-projection 1 chunk ahead (111 Wk regs), dense head 1 chunk behind.
// Barrier counts match: 1 prologue + NCK each.
__global__ __launch_bounds__(128)
__attribute__((amdgpu_waves_per_eu(1, 1)))
void gru_pc2(const float* __restrict__ values,   // [B,T,F]
             const int*   __restrict__ lengths,  // [B]
             const float* __restrict__ Wk,       // [F,3U]
             const float* __restrict__ Wr,       // [U,3U]
             const float* __restrict__ bias,     // [2,3U]
             const float* __restrict__ dw,       // [U]
             const float* __restrict__ db,       // [1]
             float*       __restrict__ out)      // [B,T]
{
    const int tid = threadIdx.x;
    const int j   = tid & 63;
    const int w   = tid >> 6;
    const int b   = blockIdx.x;

    __shared__ __align__(16) float s_v[2][CH][40];   // staged values (dbuf)
    __shared__ float s_xp[2][CH][G3];                // x-projections (dbuf)
    __shared__ __align__(16) float s_h8[2][CH][76];  // h history (padded rows)

    const float* vbp = values + (size_t)b * TQ * FQ;
    float* ob = out + (size_t)b * TQ;

    if (w == 0) {
        // ================= CONSUMER =================
        float Rz[UQ], Rr[UQ], Rh[UQ];
#pragma unroll
        for (int u = 0; u < UQ; ++u) {
            Rz[u] = Wr[u * G3 + j];
            Rr[u] = Wr[u * G3 + 64 + j];
            Rh[u] = Wr[u * G3 + 128 + j];
        }
        const float bz = bias[G3 + j];
        const float br = bias[G3 + 64 + j];
        const float bh = bias[G3 + 128 + j];
        const int len = lengths[b];

        __builtin_amdgcn_s_barrier();            // prologue barrier

        float h = 0.0f;                          // lane j holds h_j
#pragma unroll 1
        for (int k = 0; k < NCK; ++k) {
            const int pb = k & 1;
            const int tbase = k * CH;
            // rotation prefetch of xp (next-step reads issued a step early)
            float cz = s_xp[pb][0][j];
            float cr = s_xp[pb][0][64 + j];
            float cx = s_xp[pb][0][128 + j];
#pragma unroll 1
            for (int tc = 0; tc < CH; ++tc) {
                const int tn = (tc + 1) & (CH - 1);  // tc=7 -> row0 (discarded)
                const float nz = s_xp[pb][tn][j];
                const float nr = s_xp[pb][tn][64 + j];
                const float nx = s_xp[pb][tn][128 + j];

                const int hbits = __float_as_int(h);
                float az0 = 0.f, az1 = 0.f, ar0 = 0.f, ar1 = 0.f,
                      ah0 = 0.f, ah1 = 0.f;
#pragma unroll
                for (int u = 0; u < UQ; u += 2) {
                    const float h0 = __int_as_float(
                        __builtin_amdgcn_readlane(hbits, u));
                    const float h1 = __int_as_float(
                        __builtin_amdgcn_readlane(hbits, u + 1));
                    az0 += h0 * Rz[u];     az1 += h1 * Rz[u + 1];
                    ar0 += h0 * Rr[u];     ar1 += h1 * Rr[u + 1];
                    ah0 += h0 * Rh[u];     ah1 += h1 * Rh[u + 1];
                }
                const float z  = sigmoid_f(cz + bz + (az0 + az1));
                const float r  = sigmoid_f(cr + br + (ar0 + ar1));
                const float cc = tanh_f(cx + r * (bh + (ah0 + ah1)));
                const float hn = z * h + (1.0f - z) * cc;
                h = ((tbase + tc) < len) ? hn : h;
                s_h8[pb][tc][j] = h;

                cz = nz; cr = nr; cx = nx;
            }
            asm volatile("s_waitcnt lgkmcnt(0)" ::: "memory");
            __builtin_amdgcn_s_barrier();        // once per 8 steps
        }
    } else {
        // ================= PRODUCER =================
        float Kz[FQ], Kr[FQ], Kh[FQ];
#pragma unroll
        for (int f = 0; f < FQ; ++f) {
            Kz[f] = Wk[f * G3 + j];
            Kr[f] = Wk[f * G3 + 64 + j];
            Kh[f] = Wk[f * G3 + 128 + j];
        }
        const float bz = bias[j];
        const float br = bias[64 + j];
        const float bh = bias[128 + j];
        const float dbv = db[0];
        float dwv[8];
#pragma unroll
        for (int i = 0; i < 8; ++i) dwv[i] = dw[(j & 7) * 8 + i];

        // staging geometry: lane j covers dwords j, j+64, ..., j+256 (5 regs)
        int rq[5], cq[5];
        bool act[5];
        float stg[5];
#pragma unroll
        for (int q = 0; q < 5; ++q) {
            const int idx = j + 64 * q;
            act[q] = idx < CFD;
            rq[q] = idx / FQ;
            cq[q] = idx - rq[q] * FQ;
            stg[q] = 0.0f;
        }

#define STAGE_LOAD(CK)                                                        \
        _Pragma("unroll")                                                     \
        for (int q = 0; q < 5; ++q)                                           \
            if (act[q]) stg[q] = vbp[(size_t)(CK) * CFD + j + 64 * q];
#define STAGE_WRITE(SB)                                                       \
        _Pragma("unroll")                                                     \
        for (int q = 0; q < 5; ++q)                                           \
            if (act[q]) s_v[SB][rq[q]][cq[q]] = stg[q];

#define XF(VAL, I) { az += (VAL) * Kz[I]; ar += (VAL) * Kr[I]; ah += (VAL) * Kh[I]; }
#define XPROW(BB)                                                             \
    _Pragma("unroll 1")                                                       \
    for (int row = 0; row < CH; ++row) {                                      \
        const float4* vr = (const float4*)&s_v[BB][row][0];                   \
        float az = bz, ar = br, ah = bh;                                      \
        { float4 v0 = vr[0], v1 = vr[1], v2 = vr[2];                          \
          XF(v0.x, 0)  XF(v0.y, 1)  XF(v0.z, 2)  XF(v0.w, 3)                  \
          XF(v1.x, 4)  XF(v1.y, 5)  XF(v1.z, 6)  XF(v1.w, 7)                  \
          XF(v2.x, 8)  XF(v2.y, 9)  XF(v2.z, 10) XF(v2.w, 11) }               \
        { float4 v3 = vr[3], v4 = vr[4], v5 = vr[5];                          \
          XF(v3.x, 12) XF(v3.y, 13) XF(v3.z, 14) XF(v3.w, 15)                 \
          XF(v4.x, 16) XF(v4.y, 17) XF(v4.z, 18) XF(v4.w, 19)                 \
          XF(v5.x, 20) XF(v5.y, 21) XF(v5.z, 22) XF(v5.w, 23) }               \
        { float4 v6 = vr[6], v7 = vr[7], v8 = vr[8];                          \
          float f36 = s_v[BB][row][36];                                       \
          XF(v6.x, 24) XF(v6.y, 25) XF(v6.z, 26) XF(v6.w, 27)                 \
          XF(v7.x, 28) XF(v7.y, 29) XF(v7.z, 30) XF(v7.w, 31)                 \
          XF(v8.x, 32) XF(v8.y, 33) XF(v8.z, 34) XF(v8.w, 35)                 \
          XF(f36, 36) }                                                       \
        s_xp[BB][row][j]       = az;                                          \
        s_xp[BB][row][64 + j]  = ar;                                          \
        s_xp[BB][row][128 + j] = ah;                                          \
    }

#define HEAD(HB, TB)                                                          \
    {                                                                         \
        const int e = j & 7, s = j >> 3;                                      \
        const float4* hr = (const float4*)&s_h8[HB][s][e * 8];                \
        float4 ha = hr[0], hc = hr[1];                                        \
        float pp = ha.x * dwv[0] + ha.y * dwv[1] + ha.z * dwv[2]              \
                 + ha.w * dwv[3] + hc.x * dwv[4] + hc.y * dwv[5]              \
                 + hc.z * dwv[6] + hc.w * dwv[7];                             \
        pp += __shfl_xor(pp, 1, 64);                                          \
        pp += __shfl_xor(pp, 2, 64);                                          \
        pp += __shfl_xor(pp, 4, 64);                                          \
        if (e == 0) ob[(TB) + s] = sigmoid_f(pp + dbv);                       \
    }

        // prologue: chunk0 -> s_v[0]; chunk1 -> s_v[1]; issue chunk2; xp(chunk0)
        STAGE_LOAD(0)
        asm volatile("s_waitcnt vmcnt(0)" ::: "memory");
        STAGE_WRITE(0)
        STAGE_LOAD(1)
        asm volatile("s_waitcnt vmcnt(0)" ::: "memory");
        STAGE_WRITE(1)
        STAGE_LOAD(2)
        asm volatile("s_waitcnt lgkmcnt(0)" ::: "memory");  // own s_v writes visible
        XPROW(0)
        asm volatile("s_waitcnt lgkmcnt(0)" ::: "memory");
        __builtin_amdgcn_s_barrier();            // prologue barrier (xp[0] visible)

#pragma unroll 1
        for (int k = 0; k < NCK; ++k) {
            const int pb = k & 1, nb = pb ^ 1;
            if (k > 0) HEAD((k - 1) & 1, (k - 1) * CH)
            if (k + 2 < NCK) {
                asm volatile("s_waitcnt vmcnt(0)" ::: "memory");
                STAGE_WRITE(pb)                  // chunk k+2
                if (k + 3 < NCK) STAGE_LOAD(k + 3)
            }
            if (k + 1 < NCK) XPROW(nb)           // xp chunk k+1 from s_v[nb]
            asm volatile("s_waitcnt lgkmcnt(0)" ::: "memory");
            __builtin_amdgcn_s_barrier();        // once per 8 steps
        }
        HEAD((NCK - 1) & 1, (NCK - 1) * CH)

#undef STAGE_LOAD
#undef STAGE_WRITE
#undef XF
#undef XPROW
#undef HEAD
    }
}

extern "C" void kernel_launch(void* const* d_in, const int* in_sizes, int n_in,
                              void* d_out, int out_size, void* d_ws, size_t ws_size,
                              hipStream_t stream) {
    const float* values  = (const float*)d_in[2];
    const int*   lengths = (const int*)  d_in[4];
    const float* Wk      = (const float*)d_in[5];
    const float* Wr      = (const float*)d_in[6];
    const float* bias    = (const float*)d_in[7];
    const float* dw      = (const float*)d_in[8];
    const float* db      = (const float*)d_in[9];
    float* out = (float*)d_out;

    gru_pc2<<<dim3(BQ), dim3(128), 0, stream>>>(
        values, lengths, Wk, Wr, bias, dw, db, out);
}

// Round 10
// 524.443 us; speedup vs baseline: 1.6401x; 1.2969x over previous
//
#include <hip/hip_runtime.h>

#define BQ 256
#define TQ 1024
#define FQ 37
#define UQ 64
#define G3 192
#define CH 8
#define NCK (TQ / CH)
#define CFD (CH * FQ)   // 296 dwords per staged chunk

__device__ __forceinline__ float sigmoid_f(float x) {
    return 1.0f / (1.0f + __expf(-x));
}
__device__ __forceinline__ float tanh_f(float x) {
    return 1.0f - 2.0f / (__expf(2.0f * x) + 1.0f);
}

#define PIN8(A, U) asm volatile("" : "+v"(A[U]), "+v"(A[U+1]), "+v"(A[U+2]), \
    "+v"(A[U+3]), "+v"(A[U+4]), "+v"(A[U+5]), "+v"(A[U+6]), "+v"(A[U+7]))

// 2 waves / block, producer/consumer with DISJOINT per-role loops (R9) plus
// PINNED consumer weights: R9's counters showed zero spill (WRITE=1MB) but
// VGPR=148<192 -> the allocator rematerialized ~64 Wr loads into the loop
// (L2 re-fetch every step, the residual ~2.4x over the issue model). The
// asm "+v" pins make remat illegal; consumer-alone pressure ~215 < 256 so
// residency is now the allocator's only non-spill choice.
__global__ __launch_bounds__(128)
__attribute__((amdgpu_waves_per_eu(1, 1)))
void gru_pc3(const float* __restrict__ values,   // [B,T,F]
             const int*   __restrict__ lengths,  // [B]
             const float* __restrict__ Wk,       // [F,3U]
             const float* __restrict__ Wr,       // [U,3U]
             const float* __restrict__ bias,     // [2,3U]
             const float* __restrict__ dw,       // [U]
             const float* __restrict__ db,       // [1]
             float*       __restrict__ out)      // [B,T]
{
    const int tid = threadIdx.x;
    const int j   = tid & 63;
    const int w   = tid >> 6;
    const int b   = blockIdx.x;

    __shared__ __align__(16) float s_v[2][CH][40];   // staged values (dbuf)
    __shared__ float s_xp[2][CH][G3];                // x-projections (dbuf)
    __shared__ __align__(16) float s_h8[2][CH][76];  // h history (padded rows)

    const float* vbp = values + (size_t)b * TQ * FQ;
    float* ob = out + (size_t)b * TQ;

    if (w == 0) {
        // ================= CONSUMER =================
        float Rz[UQ], Rr[UQ], Rh[UQ];
#pragma unroll
        for (int u = 0; u < UQ; ++u) {
            Rz[u] = Wr[u * G3 + j];
            Rr[u] = Wr[u * G3 + 64 + j];
            Rh[u] = Wr[u * G3 + 128 + j];
        }
        // pin all 192 weights: no remat, no sinking
#pragma unroll
        for (int u = 0; u < UQ; u += 8) { PIN8(Rz, u); PIN8(Rr, u); PIN8(Rh, u); }

        const float bh = bias[G3 + 128 + j];     // only h-gate bias stays here
        const int len = lengths[b];

        __builtin_amdgcn_s_barrier();            // prologue barrier

        float h = 0.0f;                          // lane j holds h_j
#pragma unroll 1
        for (int k = 0; k < NCK; ++k) {
            const int pb = k & 1;
            const int tbase = k * CH;
            // rotation prefetch of xp (next-step reads issued a step early)
            float cz = s_xp[pb][0][j];
            float cr = s_xp[pb][0][64 + j];
            float cx = s_xp[pb][0][128 + j];
#pragma unroll 1
            for (int tc = 0; tc < CH; ++tc) {
                const int tn = (tc + 1) & (CH - 1);  // tc=7 -> row0 (discarded)
                const float nz = s_xp[pb][tn][j];
                const float nr = s_xp[pb][tn][64 + j];
                const float nx = s_xp[pb][tn][128 + j];

                const int hbits = __float_as_int(h);
                float az0 = 0.f, az1 = 0.f, ar0 = 0.f, ar1 = 0.f,
                      ah0 = 0.f, ah1 = 0.f;
#pragma unroll
                for (int u = 0; u < UQ; u += 2) {
                    const float h0 = __int_as_float(
                        __builtin_amdgcn_readlane(hbits, u));
                    const float h1 = __int_as_float(
                        __builtin_amdgcn_readlane(hbits, u + 1));
                    az0 += h0 * Rz[u];     az1 += h1 * Rz[u + 1];
                    ar0 += h0 * Rr[u];     ar1 += h1 * Rr[u + 1];
                    ah0 += h0 * Rh[u];     ah1 += h1 * Rh[u + 1];
                    if ((u & 15) == 14) __builtin_amdgcn_sched_barrier(0);
                }
                const float z  = sigmoid_f(cz + (az0 + az1));
                const float r  = sigmoid_f(cr + (ar0 + ar1));
                const float cc = tanh_f(cx + r * (bh + (ah0 + ah1)));
                const float hn = z * h + (1.0f - z) * cc;
                h = ((tbase + tc) < len) ? hn : h;
                s_h8[pb][tc][j] = h;

                cz = nz; cr = nr; cx = nx;
            }
            asm volatile("s_waitcnt lgkmcnt(0)" ::: "memory");
            __builtin_amdgcn_s_barrier();        // once per 8 steps
        }
    } else {
        // ================= PRODUCER =================
        float Kz[FQ], Kr[FQ], Kh[FQ];
#pragma unroll
        for (int f = 0; f < FQ; ++f) {
            Kz[f] = Wk[f * G3 + j];
            Kr[f] = Wk[f * G3 + 64 + j];
            Kh[f] = Wk[f * G3 + 128 + j];
        }
        // fold recurrent bias for z,r into the x-projection (shortens the
        // consumer's post-barrier chain); h-gate bias must stay separate.
        const float bz = bias[j] + bias[G3 + j];
        const float br = bias[64 + j] + bias[G3 + 64 + j];
        const float bh = bias[128 + j];
        const float dbv = db[0];
        float dwv[8];
#pragma unroll
        for (int i = 0; i < 8; ++i) dwv[i] = dw[(j & 7) * 8 + i];

        // staging geometry: lane j covers dwords j, j+64, ..., j+256 (5 regs)
        int rq[5], cq[5];
        bool act[5];
        float stg[5];
#pragma unroll
        for (int q = 0; q < 5; ++q) {
            const int idx = j + 64 * q;
            act[q] = idx < CFD;
            rq[q] = idx / FQ;
            cq[q] = idx - rq[q] * FQ;
            stg[q] = 0.0f;
        }

#define STAGE_LOAD(CK)                                                        \
        _Pragma("unroll")                                                     \
        for (int q = 0; q < 5; ++q)                                           \
            if (act[q]) stg[q] = vbp[(size_t)(CK) * CFD + j + 64 * q];
#define STAGE_WRITE(SB)                                                       \
        _Pragma("unroll")                                                     \
        for (int q = 0; q < 5; ++q)                                           \
            if (act[q]) s_v[SB][rq[q]][cq[q]] = stg[q];

#define XF(VAL, I) { az += (VAL) * Kz[I]; ar += (VAL) * Kr[I]; ah += (VAL) * Kh[I]; }
#define XPROW(BB)                                                             \
    _Pragma("unroll 1")                                                       \
    for (int row = 0; row < CH; ++row) {                                      \
        const float4* vr = (const float4*)&s_v[BB][row][0];                   \
        float az = bz, ar = br, ah = bh;                                      \
        { float4 v0 = vr[0], v1 = vr[1], v2 = vr[2];                          \
          XF(v0.x, 0)  XF(v0.y, 1)  XF(v0.z, 2)  XF(v0.w, 3)                  \
          XF(v1.x, 4)  XF(v1.y, 5)  XF(v1.z, 6)  XF(v1.w, 7)                  \
          XF(v2.x, 8)  XF(v2.y, 9)  XF(v2.z, 10) XF(v2.w, 11) }               \
        { float4 v3 = vr[3], v4 = vr[4], v5 = vr[5];                          \
          XF(v3.x, 12) XF(v3.y, 13) XF(v3.z, 14) XF(v3.w, 15)                 \
          XF(v4.x, 16) XF(v4.y, 17) XF(v4.z, 18) XF(v4.w, 19)                 \
          XF(v5.x, 20) XF(v5.y, 21) XF(v5.z, 22) XF(v5.w, 23) }               \
        { float4 v6 = vr[6], v7 = vr[7], v8 = vr[8];                          \
          float f36 = s_v[BB][row][36];                                       \
          XF(v6.x, 24) XF(v6.y, 25) XF(v6.z, 26) XF(v6.w, 27)                 \
          XF(v7.x, 28) XF(v7.y, 29) XF(v7.z, 30) XF(v7.w, 31)                 \
          XF(v8.x, 32) XF(v8.y, 33) XF(v8.z, 34) XF(v8.w, 35)                 \
          XF(f36, 36) }                                                       \
        s_xp[BB][row][j]       = az;                                          \
        s_xp[BB][row][64 + j]  = ar;                                          \
        s_xp[BB][row][128 + j] = ah;                                          \
    }

#define HEAD(HB, TB)                                                          \
    {                                                                         \
        const int e = j & 7, s = j >> 3;                                      \
        const float4* hr = (const float4*)&s_h8[HB][s][e * 8];                \
        float4 ha = hr[0], hc = hr[1];                                        \
        float pp = ha.x * dwv[0] + ha.y * dwv[1] + ha.z * dwv[2]              \
                 + ha.w * dwv[3] + hc.x * dwv[4] + hc.y * dwv[5]              \
                 + hc.z * dwv[6] + hc.w * dwv[7];                             \
        pp += __shfl_xor(pp, 1, 64);                                          \
        pp += __shfl_xor(pp, 2, 64);                                          \
        pp += __shfl_xor(pp, 4, 64);                                          \
        if (e == 0) ob[(TB) + s] = sigmoid_f(pp + dbv);                       \
    }

        // prologue: chunk0 -> s_v[0]; chunk1 -> s_v[1]; issue chunk2; xp(chunk0)
        STAGE_LOAD(0)
        asm volatile("s_waitcnt vmcnt(0)" ::: "memory");
        STAGE_WRITE(0)
        STAGE_LOAD(1)
        asm volatile("s_waitcnt vmcnt(0)" ::: "memory");
        STAGE_WRITE(1)
        STAGE_LOAD(2)
        asm volatile("s_waitcnt lgkmcnt(0)" ::: "memory");  // own s_v writes visible
        XPROW(0)
        asm volatile("s_waitcnt lgkmcnt(0)" ::: "memory");
        __builtin_amdgcn_s_barrier();            // prologue barrier (xp[0] visible)

#pragma unroll 1
        for (int k = 0; k < NCK; ++k) {
            const int pb = k & 1, nb = pb ^ 1;
            if (k > 0) HEAD((k - 1) & 1, (k - 1) * CH)
            if (k + 2 < NCK) {
                asm volatile("s_waitcnt vmcnt(0)" ::: "memory");
                STAGE_WRITE(pb)                  // chunk k+2
                if (k + 3 < NCK) STAGE_LOAD(k + 3)
            }
            if (k + 1 < NCK) XPROW(nb)           // xp chunk k+1 from s_v[nb]
            asm volatile("s_waitcnt lgkmcnt(0)" ::: "memory");
            __builtin_amdgcn_s_barrier();        // once per 8 steps
        }
        HEAD((NCK - 1) & 1, (NCK - 1) * CH)

#undef STAGE_LOAD
#undef STAGE_WRITE
#undef XF
#undef XPROW
#undef HEAD
    }
}

extern "C" void kernel_launch(void* const* d_in, const int* in_sizes, int n_in,
                              void* d_out, int out_size, void* d_ws, size_t ws_size,
                              hipStream_t stream) {
    const float* values  = (const float*)d_in[2];
    const int*   lengths = (const int*)  d_in[4];
    const float* Wk      = (const float*)d_in[5];
    const float* Wr      = (const float*)d_in[6];
    const float* bias    = (const float*)d_in[7];
    const float* dw      = (const float*)d_in[8];
    const float* db      = (const float*)d_in[9];
    float* out = (float*)d_out;

    gru_pc3<<<dim3(BQ), dim3(128), 0, stream>>>(
        values, lengths, Wk, Wr, bias, dw, db, out);
}